// Round 15
// baseline (182.349 us; speedup 1.0000x reference)
//
#include <hip/hip_runtime.h>
#include <hip/hip_fp16.h>
#include <cstdint>

#define B_   4
#define S_   2048
#define HID_ 1024
#define NH_  16
#define HD_  64
#define M_   (B_ * S_)   // 8192

using f16   = _Float16;
using f16x4 = __attribute__((ext_vector_type(4))) _Float16;
using f16x8 = __attribute__((ext_vector_type(8))) _Float16;
using f32x4 = __attribute__((ext_vector_type(4))) float;
using u32x4 = __attribute__((ext_vector_type(4))) unsigned int;

// async 16B global -> LDS (HW writes wave-uniform base + lane*16)
__device__ __forceinline__ void g2lds16(const void* g, void* l) {
  __builtin_amdgcn_global_load_lds(
      (__attribute__((address_space(1))) void*)(uintptr_t)g,
      (__attribute__((address_space(3))) void*)(uint32_t)(uintptr_t)l,
      16, 0, 0);
}

// pack 2 f32 -> 2 f16 in one u32 (round-to-zero): src0 -> lo16, src1 -> hi16
__device__ __forceinline__ unsigned int pk16(float a, float b) {
  unsigned int r;
  asm("v_cvt_pkrtz_f16_f32 %0, %1, %2" : "=v"(r) : "v"(a), "v"(b));
  return r;
}

// key permutation for K-staging (R6-validated): staged row -> true key bit-shuffle
// [c1 c0 g1 g0 r1 r0] -> [c1 g1 g0 c0 r1 r0]; QK D-regs land on keys kk*32+g*8+..
#define PIDX(r) (((r) & 32) | (((r) & 12) << 1) | ((((r) >> 4) & 1) << 2) | ((r) & 3))

#define CS_ 0.180336880111120426f  // 0.125 * log2(e)

// ---------------- f32 -> f16 convert ----------------
__global__ void cvt_f32_f16_k(const float* __restrict__ src, f16* __restrict__ dst, int n4) {
  int i = blockIdx.x * blockDim.x + threadIdx.x;
  if (i >= n4) return;
  float4 v = ((const float4*)src)[i];
  f16x4 h;
  h[0] = (f16)v.x; h[1] = (f16)v.y; h[2] = (f16)v.z; h[3] = (f16)v.w;
  ((f16x4*)dst)[i] = h;
}

// ---------------- Q projection GEMM (validated structure) ----------------
__global__ __launch_bounds__(256) void proj_q_k(
    const f16* __restrict__ A, const f16* __restrict__ W,
    const float* __restrict__ bq, f16* __restrict__ Out) {
  __shared__ __align__(16) f16 As[128 * 64];
  __shared__ __align__(16) f16 Bs[128 * 64];
  const int tid = threadIdx.x;
  const int l   = tid & 63;
  const int w   = tid >> 6;
  const int lr  = l & 15;
  const int lk  = (l >> 4) * 8;
  const int col0 = blockIdx.x * 128;   // 0..7
  const int row0 = blockIdx.y * 128;   // 0..63
  const int wr = (w >> 1) * 64;
  const int wc = (w & 1) * 64;

  f32x4 acc[4][4] = {};

  for (int kt = 0; kt < 16; ++kt) {
    const int k0 = kt * 64;
#pragma unroll
    for (int i = 0; i < 4; ++i) {
      const int c   = tid + i * 256;
      const int row = c >> 3;
      const int cb  = (c ^ row) & 7;
      g2lds16(A + (size_t)(row0 + row) * 1024 + k0 + cb * 8,
              As + (w * 64 + i * 256) * 8);
      g2lds16(W + (size_t)(col0 + row) * 1024 + k0 + cb * 8,
              Bs + (w * 64 + i * 256) * 8);
    }
    asm volatile("s_waitcnt vmcnt(0)" ::: "memory");
    __syncthreads();

#pragma unroll
    for (int kk = 0; kk < 64; kk += 32) {
      const int x = (kk + lk) >> 3;
      f16x8 af[4], bf[4];
#pragma unroll
      for (int m = 0; m < 4; ++m) {
        const int row = wr + m * 16 + lr;
        af[m] = *(const f16x8*)(As + (row * 8 + ((x ^ row) & 7)) * 8);
      }
#pragma unroll
      for (int n = 0; n < 4; ++n) {
        const int row = wc + n * 16 + lr;
        bf[n] = *(const f16x8*)(Bs + (row * 8 + ((x ^ row) & 7)) * 8);
      }
#pragma unroll
      for (int m = 0; m < 4; ++m)
#pragma unroll
        for (int n = 0; n < 4; ++n)
          acc[m][n] = __builtin_amdgcn_mfma_f32_16x16x32_f16(af[m], bf[n], acc[m][n], 0, 0, 0);
    }
    __syncthreads();
  }

#pragma unroll
  for (int n = 0; n < 4; ++n) {
    const int cp = col0 + wc + n * 16 + lr;
    const float bb = bq[cp];
#pragma unroll
    for (int m = 0; m < 4; ++m) {
      const int rbase = row0 + wr + m * 16 + (l >> 4) * 4;
#pragma unroll
      for (int r = 0; r < 4; ++r)
        Out[(size_t)(rbase + r) * 1024 + cp] = (f16)(acc[m][n][r] + bb);
    }
  }
}

// ---------------- fused K+V projection -> keff + Vt directly ----------------
// Same validated GEMM structure; two B-tiles share one A-tile. Epilogue applies
// prep_kv's (validated) keff formula to the f32 accumulators and writes
// keff[bh][s][d] (pre-scaled by CS_) and Vt[bh][d][s] without intermediates.
__global__ __launch_bounds__(256) void proj_kv_k(
    const f16* __restrict__ A, const f16* __restrict__ Wk_, const f16* __restrict__ Wv_,
    const float* __restrict__ bk, const float* __restrict__ bv,
    f16* __restrict__ Keff, f16* __restrict__ Vt) {
  __shared__ __align__(16) f16 As[128 * 64];
  __shared__ __align__(16) f16 Bk[128 * 64];
  __shared__ __align__(16) f16 Bv[128 * 64];
  const int tid = threadIdx.x;
  const int l   = tid & 63;
  const int w   = tid >> 6;
  const int lr  = l & 15;
  const int lk  = (l >> 4) * 8;
  const int col0 = blockIdx.x * 128;   // 0..7 (within 1024)
  const int row0 = blockIdx.y * 128;   // 0..63
  const int wr = (w >> 1) * 64;
  const int wc = (w & 1) * 64;

  f32x4 kacc[4][4] = {};
  f32x4 vacc[4][4] = {};

  for (int kt = 0; kt < 16; ++kt) {
    const int k0 = kt * 64;
#pragma unroll
    for (int i = 0; i < 4; ++i) {
      const int c   = tid + i * 256;
      const int row = c >> 3;
      const int cb  = (c ^ row) & 7;
      g2lds16(A + (size_t)(row0 + row) * 1024 + k0 + cb * 8,
              As + (w * 64 + i * 256) * 8);
      g2lds16(Wk_ + (size_t)(col0 + row) * 1024 + k0 + cb * 8,
              Bk + (w * 64 + i * 256) * 8);
      g2lds16(Wv_ + (size_t)(col0 + row) * 1024 + k0 + cb * 8,
              Bv + (w * 64 + i * 256) * 8);
    }
    asm volatile("s_waitcnt vmcnt(0)" ::: "memory");
    __syncthreads();

#pragma unroll
    for (int kk = 0; kk < 64; kk += 32) {
      const int x = (kk + lk) >> 3;
      f16x8 af[4], bkf[4], bvf[4];
#pragma unroll
      for (int m = 0; m < 4; ++m) {
        const int row = wr + m * 16 + lr;
        af[m] = *(const f16x8*)(As + (row * 8 + ((x ^ row) & 7)) * 8);
      }
#pragma unroll
      for (int n = 0; n < 4; ++n) {
        const int row = wc + n * 16 + lr;
        bkf[n] = *(const f16x8*)(Bk + (row * 8 + ((x ^ row) & 7)) * 8);
        bvf[n] = *(const f16x8*)(Bv + (row * 8 + ((x ^ row) & 7)) * 8);
      }
#pragma unroll
      for (int m = 0; m < 4; ++m)
#pragma unroll
        for (int n = 0; n < 4; ++n) {
          kacc[m][n] = __builtin_amdgcn_mfma_f32_16x16x32_f16(af[m], bkf[n], kacc[m][n], 0, 0, 0);
          vacc[m][n] = __builtin_amdgcn_mfma_f32_16x16x32_f16(af[m], bvf[n], vacc[m][n], 0, 0, 0);
        }
    }
    __syncthreads();
  }

  // epilogue: keff = CS_*(k/8 + softsign(softsign(k)/8) + v); vt transposed
#pragma unroll
  for (int n = 0; n < 4; ++n) {
    const int cp = col0 + wc + n * 16 + lr;    // 0..1023
    const int h = cp >> 6, d = cp & 63;
    const float bbk = bk[cp], bbv = bv[cp];
#pragma unroll
    for (int m = 0; m < 4; ++m) {
      const int rbase = row0 + wr + m * 16 + (l >> 4) * 4;
      const int b = rbase >> 11;
      const int s0 = rbase & 2047;
      const size_t bh64 = (size_t)(b * 16 + h);
      f16x4 vv4;
#pragma unroll
      for (int r = 0; r < 4; ++r) {
        const float kf = kacc[m][n][r] + bbk;
        const float vf = vacc[m][n][r] + bbv;
        const float s1 = kf / (1.f + fabsf(kf));
        const float t  = s1 * 0.125f;
        const float s2 = t / (1.f + fabsf(t));
        Keff[(bh64 * S_ + s0 + r) * 64 + d] = (f16)((kf * 0.125f + s2 + vf) * CS_);
        vv4[r] = (f16)vf;
      }
      *(f16x4*)(&Vt[(bh64 * 64 + d) * S_ + s0]) = vv4;
    }
  }
}

// ---------------- flash attention: 4 waves/SIMD (2 blocks/CU), qb=2 ---------------
// block = (bh, qtile of 256 rows), 8 waves x 32 q (qb=0,1); K/V tiles 64, dbuf.
// R14-validated compute body (raw v_exp_f32); only q-indexing changed.
__global__ __launch_bounds__(512) void attn_k(
    const f16* __restrict__ Q,     // [8192][1024]
    const f16* __restrict__ Keff,  // [64][2048][64]  (pre-scaled by CS_)
    const f16* __restrict__ Vt,    // [64][64][2048]
    const int* __restrict__ mask,  // [4][2048]
    float* __restrict__ Out) {     // [8192][1024] f32
  __shared__ __align__(16) f16 Kl[2][64 * 64];
  __shared__ __align__(16) f16 Vl[2][64 * 64];
  const int bh = blockIdx.x, qt = blockIdx.y;   // qt 0..7
  const int b = bh >> 4, h = bh & 15;
  const int tid = threadIdx.x;
  const int l = tid & 63, w = tid >> 6;   // w in 0..7
  const int lr = l & 15, g = l >> 4;

  // Q fragments (B-operand of mfma(kf,qf)); zeroed if q-row masked.
  f16x8 qf[2][2];
#pragma unroll
  for (int qb = 0; qb < 2; ++qb) {
    const int qrow = qt * 256 + w * 32 + qb * 16 + lr;
    const f16* qs = Q + (size_t)(b * S_ + qrow) * 1024 + h * 64 + g * 8;
    qf[qb][0] = *(const f16x8*)(qs);
    qf[qb][1] = *(const f16x8*)(qs + 32);
    if (mask[b * S_ + qrow] == 0) {
      qf[qb][0] = (f16x8)(f16)0;
      qf[qb][1] = (f16x8)(f16)0;
    }
  }

  // staging GLOBAL pointers (one K chunk + one V chunk per thread; 512 chunks each)
  const int srow = tid >> 3, scl = tid & 7;
  const int sc = scl ^ (srow & 7);
  const f16* kg = Keff + ((size_t)bh * S_ + PIDX(srow)) * 64 + sc * 8;
  const f16* vg = Vt + ((size_t)bh * 64 + srow) * 2048 + sc * 8;

  f32x4 ctx[2][4] = {};    // ctx[qb][db][r] = O[q=lr][d=db*16+g*4+r]
  float lacc[2] = {0.f, 0.f};

#define STAGE(bf, t)                                                           \
  {                                                                            \
    g2lds16(kg + (size_t)(t) * 4096, &Kl[bf][(w * 64) * 8]);                   \
    g2lds16(vg + (size_t)(t) * 64, &Vl[bf][(w * 64) * 8]);                     \
  }

  STAGE(0, 0);
  asm volatile("s_waitcnt vmcnt(0)" ::: "memory");
  __syncthreads();

  for (int kt = 0; kt < 32; ++kt) {
    const int cur = kt & 1;
    if (kt < 31) STAGE(cur ^ 1, kt + 1);

    // ---- QK + softmax-lite, in cb-pair slices (validated) ----
    f16x8 pf[2][2];   // pf[qb][cbp]: P[q=lr][true keys cbp*32 + g*8 .. +7]
#pragma unroll
    for (int cbp = 0; cbp < 2; ++cbp) {
      f32x4 sv[2][2] = {};
      __builtin_amdgcn_s_setprio(1);
#pragma unroll
      for (int kk = 0; kk < 2; ++kk)
#pragma unroll
        for (int cc = 0; cc < 2; ++cc) {
          const int row = (cbp * 2 + cc) * 16 + lr;
          const f16x8 kf = *(const f16x8*)(&Kl[cur][(row * 8 + ((kk * 4 + g) ^ (row & 7))) * 8]);
#pragma unroll
          for (int qb = 0; qb < 2; ++qb)
            sv[qb][cc] = __builtin_amdgcn_mfma_f32_16x16x32_f16(kf, qf[qb][kk], sv[qb][cc], 0, 0, 0);
        }
      __builtin_amdgcn_s_setprio(0);
#pragma unroll
      for (int qb = 0; qb < 2; ++qb) {
        float pv[2][4];
        float s = 0.f;
#pragma unroll
        for (int cc = 0; cc < 2; ++cc)
#pragma unroll
          for (int r = 0; r < 4; ++r) {
            const float pe = __builtin_amdgcn_exp2f(sv[qb][cc][r]);  // raw v_exp_f32
            pv[cc][r] = pe;
            s += pe;
          }
        lacc[qb] += s;
        u32x4 pw = {pk16(pv[0][0], pv[0][1]), pk16(pv[0][2], pv[0][3]),
                    pk16(pv[1][0], pv[1][1]), pk16(pv[1][2], pv[1][3])};
        pf[qb][cbp] = __builtin_bit_cast(f16x8, pw);
      }
    }

    // ---- PV: mfma(vf, pf) ----
    __builtin_amdgcn_s_setprio(1);
#pragma unroll
    for (int kk = 0; kk < 2; ++kk)
#pragma unroll
      for (int db = 0; db < 4; ++db) {
        const int row = db * 16 + lr;
        const f16x8 vf = *(const f16x8*)(&Vl[cur][(row * 8 + ((kk * 4 + g) ^ (row & 7))) * 8]);
#pragma unroll
        for (int qb = 0; qb < 2; ++qb)
          ctx[qb][db] = __builtin_amdgcn_mfma_f32_16x16x32_f16(vf, pf[qb][kk], ctx[qb][db], 0, 0, 0);
      }
    __builtin_amdgcn_s_setprio(0);

    asm volatile("s_waitcnt vmcnt(0)" ::: "memory");
    __syncthreads();
  }

  // ---- finalize: cross-group sum (shfl), divide, store f32x4 ----
#pragma unroll
  for (int qb = 0; qb < 2; ++qb) {
    float ls = lacc[qb];
    ls += __shfl_xor(ls, 16);
    ls += __shfl_xor(ls, 32);
    const float linv = 1.0f / ls;
    const int qrow = qt * 256 + w * 32 + qb * 16 + lr;
    float* op = Out + (size_t)(b * S_ + qrow) * 1024 + h * 64 + g * 4;
#pragma unroll
    for (int db = 0; db < 4; ++db) {
      f32x4 o = ctx[qb][db] * linv;
      *(f32x4*)(op + db * 16) = o;
    }
  }
}

extern "C" void kernel_launch(void* const* d_in, const int* in_sizes, int n_in,
                              void* d_out, int out_size, void* d_ws, size_t ws_size,
                              hipStream_t stream) {
  const float* hs = (const float*)d_in[0];
  const float* Wq = (const float*)d_in[1];
  const float* bq = (const float*)d_in[2];
  const float* Wk = (const float*)d_in[3];
  const float* bk = (const float*)d_in[4];
  const float* Wv = (const float*)d_in[5];
  const float* bv = (const float*)d_in[6];
  const int* mask = (const int*)d_in[7];
  float* out = (float*)d_out;

  f16* hsF  = (f16*)d_ws;                       // 8192*1024
  f16* wF   = hsF + (size_t)M_ * HID_;          // 3*1024*1024 (Wq, Wk, Wv)
  f16* qF   = wF + 3ull * HID_ * HID_;          // 8192*1024
  f16* keff = qF + (size_t)M_ * HID_;           // 64*2048*64
  f16* vt   = keff + (size_t)M_ * HID_;         // 64*64*2048

  cvt_f32_f16_k<<<dim3((M_ * HID_) / 1024), 256, 0, stream>>>(hs, hsF, (M_ * HID_) / 4);
  cvt_f32_f16_k<<<dim3((HID_ * HID_) / 1024), 256, 0, stream>>>(Wq, wF, (HID_ * HID_) / 4);
  cvt_f32_f16_k<<<dim3((HID_ * HID_) / 1024), 256, 0, stream>>>(Wk, wF + (size_t)HID_ * HID_, (HID_ * HID_) / 4);
  cvt_f32_f16_k<<<dim3((HID_ * HID_) / 1024), 256, 0, stream>>>(Wv, wF + 2ull * (size_t)HID_ * HID_, (HID_ * HID_) / 4);

  proj_q_k<<<dim3(8, 64), 256, 0, stream>>>(hsF, wF, bq, qF);
  proj_kv_k<<<dim3(8, 64), 256, 0, stream>>>(hsF, wF + (size_t)HID_ * HID_,
                                             wF + 2ull * (size_t)HID_ * HID_, bk, bv, keff, vt);
  attn_k<<<dim3(64, 8), 512, 0, stream>>>(qF, keff, vt, mask, out);
}

// Round 16
// 165.438 us; speedup vs baseline: 1.1022x; 1.1022x over previous
//
#include <hip/hip_runtime.h>
#include <hip/hip_fp16.h>
#include <cstdint>

#define B_   4
#define S_   2048
#define HID_ 1024
#define NH_  16
#define HD_  64
#define M_   (B_ * S_)   // 8192

using f16   = _Float16;
using f16x4 = __attribute__((ext_vector_type(4))) _Float16;
using f16x8 = __attribute__((ext_vector_type(8))) _Float16;
using f32x4 = __attribute__((ext_vector_type(4))) float;
using u32x4 = __attribute__((ext_vector_type(4))) unsigned int;

// async 16B global -> LDS (HW writes wave-uniform base + lane*16)
__device__ __forceinline__ void g2lds16(const void* g, void* l) {
  __builtin_amdgcn_global_load_lds(
      (__attribute__((address_space(1))) void*)(uintptr_t)g,
      (__attribute__((address_space(3))) void*)(uint32_t)(uintptr_t)l,
      16, 0, 0);
}

// pack 2 f32 -> 2 f16 in one u32 (round-to-zero): src0 -> lo16, src1 -> hi16
__device__ __forceinline__ unsigned int pk16(float a, float b) {
  unsigned int r;
  asm("v_cvt_pkrtz_f16_f32 %0, %1, %2" : "=v"(r) : "v"(a), "v"(b));
  return r;
}

// key permutation for K-staging (R6-validated): staged row -> true key bit-shuffle
// [c1 c0 g1 g0 r1 r0] -> [c1 g1 g0 c0 r1 r0]; QK D-regs land on keys kk*32+g*8+..
#define PIDX(r) (((r) & 32) | (((r) & 12) << 1) | ((((r) >> 4) & 1) << 2) | ((r) & 3))

#define CS_ 0.180336880111120426f  // 0.125 * log2(e)

// ---------------- fused f32 -> f16 convert (hs + Wq + Wk + Wv, one launch) --------
__global__ void cvt_all_k(const float* __restrict__ hs, const float* __restrict__ wq,
                          const float* __restrict__ wk, const float* __restrict__ wv,
                          f16* __restrict__ hsF, f16* __restrict__ wF) {
  const int bid = blockIdx.x, tid = threadIdx.x;
  const float* src;
  f16* dst;
  int i;
  if (bid < 8192) {                 // hs: 2M float4
    src = hs; dst = hsF; i = bid * 256 + tid;
  } else {                          // weights: 256K float4 each
    const int r = (bid - 8192) >> 10;
    src = (r == 0) ? wq : ((r == 1) ? wk : wv);
    dst = wF + (size_t)r * HID_ * HID_;
    i = ((bid - 8192) & 1023) * 256 + tid;
  }
  float4 v = ((const float4*)src)[i];
  f16x4 h;
  h[0] = (f16)v.x; h[1] = (f16)v.y; h[2] = (f16)v.z; h[3] = (f16)v.w;
  ((f16x4*)dst)[i] = h;
}

// ---------------- fused QKV projection GEMM (R14-validated) ----------------
__global__ __launch_bounds__(256) void proj_gemm_k(
    const f16* __restrict__ A, const f16* __restrict__ W,
    const float* __restrict__ bq, const float* __restrict__ bk, const float* __restrict__ bv,
    f16* __restrict__ Out) {
  __shared__ __align__(16) f16 As[128 * 64];
  __shared__ __align__(16) f16 Bs[128 * 64];
  const int tid = threadIdx.x;
  const int l   = tid & 63;
  const int w   = tid >> 6;
  const int lr  = l & 15;
  const int lk  = (l >> 4) * 8;
  const int col0 = blockIdx.x * 128;
  const int row0 = blockIdx.y * 128;
  const int wr = (w >> 1) * 64;
  const int wc = (w & 1) * 64;

  f32x4 acc[4][4] = {};

  for (int kt = 0; kt < 16; ++kt) {
    const int k0 = kt * 64;
#pragma unroll
    for (int i = 0; i < 4; ++i) {
      const int c   = tid + i * 256;
      const int row = c >> 3;
      const int cb  = (c ^ row) & 7;
      g2lds16(A + (size_t)(row0 + row) * 1024 + k0 + cb * 8,
              As + (w * 64 + i * 256) * 8);
      g2lds16(W + (size_t)(col0 + row) * 1024 + k0 + cb * 8,
              Bs + (w * 64 + i * 256) * 8);
    }
    asm volatile("s_waitcnt vmcnt(0)" ::: "memory");
    __syncthreads();

#pragma unroll
    for (int kk = 0; kk < 64; kk += 32) {
      const int x = (kk + lk) >> 3;
      f16x8 af[4], bf[4];
#pragma unroll
      for (int m = 0; m < 4; ++m) {
        const int row = wr + m * 16 + lr;
        af[m] = *(const f16x8*)(As + (row * 8 + ((x ^ row) & 7)) * 8);
      }
#pragma unroll
      for (int n = 0; n < 4; ++n) {
        const int row = wc + n * 16 + lr;
        bf[n] = *(const f16x8*)(Bs + (row * 8 + ((x ^ row) & 7)) * 8);
      }
#pragma unroll
      for (int m = 0; m < 4; ++m)
#pragma unroll
        for (int n = 0; n < 4; ++n)
          acc[m][n] = __builtin_amdgcn_mfma_f32_16x16x32_f16(af[m], bf[n], acc[m][n], 0, 0, 0);
    }
    __syncthreads();
  }

  const int proj = col0 >> 10;
  const float* bias = (proj == 0) ? bq : ((proj == 1) ? bk : bv);
  f16* outp = Out + (size_t)proj * ((size_t)M_ * HID_);
#pragma unroll
  for (int n = 0; n < 4; ++n) {
    const int col = col0 + wc + n * 16 + lr;
    const int cp  = col & 1023;
    const float bb = bias[cp];
#pragma unroll
    for (int m = 0; m < 4; ++m) {
      const int rbase = row0 + wr + m * 16 + (l >> 4) * 4;
#pragma unroll
      for (int r = 0; r < 4; ++r)
        outp[(size_t)(rbase + r) * 1024 + cp] = (f16)(acc[m][n][r] + bb);
    }
  }
}

// ---------------- keff + V-transpose prep (R14-validated) ----------------
// keff_s = CS_ * (k/8 + softsign(softsign(k)/8) + v)
__global__ __launch_bounds__(256) void prep_kv_k(
    const f16* __restrict__ Kp, const f16* __restrict__ Vp,
    f16* __restrict__ Keff, f16* __restrict__ Vt) {
  const int bh = blockIdx.x;  // 64
  const int st = blockIdx.y;  // 32
  const int b = bh >> 4, h = bh & 15;
  const int tid = threadIdx.x;
#pragma unroll
  for (int i = 0; i < 2; ++i) {
    const int c  = tid + i * 256;
    const int sl = c >> 3, cb = c & 7;
    const int s  = st * 64 + sl;
    const size_t src = (size_t)(b * S_ + s) * 1024 + h * 64 + cb * 8;
    const f16x8 kv = *(const f16x8*)(Kp + src);
    const f16x8 vv = *(const f16x8*)(Vp + src);
    f16x8 ke;
#pragma unroll
    for (int j = 0; j < 8; ++j) {
      const float kf = (float)kv[j], vf = (float)vv[j];
      const float s1 = kf / (1.f + fabsf(kf));
      const float t  = s1 * 0.125f;
      const float s2 = t / (1.f + fabsf(t));
      ke[j] = (f16)((kf * 0.125f + s2 + vf) * CS_);
    }
    *(f16x8*)(Keff + ((size_t)bh * S_ + s) * 64 + cb * 8) = ke;
#pragma unroll
    for (int j = 0; j < 8; ++j)
      Vt[((size_t)bh * 64 + cb * 8 + j) * S_ + s] = vv[j];
  }
}

// ---------------- flash attention (R15-validated): qb=2, 2 blocks/CU --------------
__global__ __launch_bounds__(512) void attn_k(
    const f16* __restrict__ Q,     // [8192][1024]
    const f16* __restrict__ Keff,  // [64][2048][64]  (pre-scaled by CS_)
    const f16* __restrict__ Vt,    // [64][64][2048]
    const int* __restrict__ mask,  // [4][2048]
    float* __restrict__ Out) {     // [8192][1024] f32
  __shared__ __align__(16) f16 Kl[2][64 * 64];
  __shared__ __align__(16) f16 Vl[2][64 * 64];
  const int bh = blockIdx.x, qt = blockIdx.y;   // qt 0..7
  const int b = bh >> 4, h = bh & 15;
  const int tid = threadIdx.x;
  const int l = tid & 63, w = tid >> 6;   // w in 0..7
  const int lr = l & 15, g = l >> 4;

  // Q fragments (B-operand of mfma(kf,qf)); zeroed if q-row masked.
  f16x8 qf[2][2];
#pragma unroll
  for (int qb = 0; qb < 2; ++qb) {
    const int qrow = qt * 256 + w * 32 + qb * 16 + lr;
    const f16* qs = Q + (size_t)(b * S_ + qrow) * 1024 + h * 64 + g * 8;
    qf[qb][0] = *(const f16x8*)(qs);
    qf[qb][1] = *(const f16x8*)(qs + 32);
    if (mask[b * S_ + qrow] == 0) {
      qf[qb][0] = (f16x8)(f16)0;
      qf[qb][1] = (f16x8)(f16)0;
    }
  }

  // staging GLOBAL pointers (one K chunk + one V chunk per thread; 512 chunks each)
  const int srow = tid >> 3, scl = tid & 7;
  const int sc = scl ^ (srow & 7);
  const f16* kg = Keff + ((size_t)bh * S_ + PIDX(srow)) * 64 + sc * 8;
  const f16* vg = Vt + ((size_t)bh * 64 + srow) * 2048 + sc * 8;

  f32x4 ctx[2][4] = {};    // ctx[qb][db][r] = O[q=lr][d=db*16+g*4+r]
  float lacc[2] = {0.f, 0.f};

#define STAGE(bf, t)                                                           \
  {                                                                            \
    g2lds16(kg + (size_t)(t) * 4096, &Kl[bf][(w * 64) * 8]);                   \
    g2lds16(vg + (size_t)(t) * 64, &Vl[bf][(w * 64) * 8]);                     \
  }

  STAGE(0, 0);
  asm volatile("s_waitcnt vmcnt(0)" ::: "memory");
  __syncthreads();

  for (int kt = 0; kt < 32; ++kt) {
    const int cur = kt & 1;
    if (kt < 31) STAGE(cur ^ 1, kt + 1);

    // ---- QK + softmax-lite, in cb-pair slices (validated) ----
    f16x8 pf[2][2];   // pf[qb][cbp]: P[q=lr][true keys cbp*32 + g*8 .. +7]
#pragma unroll
    for (int cbp = 0; cbp < 2; ++cbp) {
      f32x4 sv[2][2] = {};
      __builtin_amdgcn_s_setprio(1);
#pragma unroll
      for (int kk = 0; kk < 2; ++kk)
#pragma unroll
        for (int cc = 0; cc < 2; ++cc) {
          const int row = (cbp * 2 + cc) * 16 + lr;
          const f16x8 kf = *(const f16x8*)(&Kl[cur][(row * 8 + ((kk * 4 + g) ^ (row & 7))) * 8]);
#pragma unroll
          for (int qb = 0; qb < 2; ++qb)
            sv[qb][cc] = __builtin_amdgcn_mfma_f32_16x16x32_f16(kf, qf[qb][kk], sv[qb][cc], 0, 0, 0);
        }
      __builtin_amdgcn_s_setprio(0);
#pragma unroll
      for (int qb = 0; qb < 2; ++qb) {
        float pv[2][4];
        float s = 0.f;
#pragma unroll
        for (int cc = 0; cc < 2; ++cc)
#pragma unroll
          for (int r = 0; r < 4; ++r) {
            const float pe = __builtin_amdgcn_exp2f(sv[qb][cc][r]);  // raw v_exp_f32
            pv[cc][r] = pe;
            s += pe;
          }
        lacc[qb] += s;
        u32x4 pw = {pk16(pv[0][0], pv[0][1]), pk16(pv[0][2], pv[0][3]),
                    pk16(pv[1][0], pv[1][1]), pk16(pv[1][2], pv[1][3])};
        pf[qb][cbp] = __builtin_bit_cast(f16x8, pw);
      }
    }

    // ---- PV: mfma(vf, pf) ----
    __builtin_amdgcn_s_setprio(1);
#pragma unroll
    for (int kk = 0; kk < 2; ++kk)
#pragma unroll
      for (int db = 0; db < 4; ++db) {
        const int row = db * 16 + lr;
        const f16x8 vf = *(const f16x8*)(&Vl[cur][(row * 8 + ((kk * 4 + g) ^ (row & 7))) * 8]);
#pragma unroll
        for (int qb = 0; qb < 2; ++qb)
          ctx[qb][db] = __builtin_amdgcn_mfma_f32_16x16x32_f16(vf, pf[qb][kk], ctx[qb][db], 0, 0, 0);
      }
    __builtin_amdgcn_s_setprio(0);

    asm volatile("s_waitcnt vmcnt(0)" ::: "memory");
    __syncthreads();
  }

  // ---- finalize: cross-group sum (shfl), divide, store f32x4 ----
#pragma unroll
  for (int qb = 0; qb < 2; ++qb) {
    float ls = lacc[qb];
    ls += __shfl_xor(ls, 16);
    ls += __shfl_xor(ls, 32);
    const float linv = 1.0f / ls;
    const int qrow = qt * 256 + w * 32 + qb * 16 + lr;
    float* op = Out + (size_t)(b * S_ + qrow) * 1024 + h * 64 + g * 4;
#pragma unroll
    for (int db = 0; db < 4; ++db) {
      f32x4 o = ctx[qb][db] * linv;
      *(f32x4*)(op + db * 16) = o;
    }
  }
}

extern "C" void kernel_launch(void* const* d_in, const int* in_sizes, int n_in,
                              void* d_out, int out_size, void* d_ws, size_t ws_size,
                              hipStream_t stream) {
  const float* hs = (const float*)d_in[0];
  const float* Wq = (const float*)d_in[1];
  const float* bq = (const float*)d_in[2];
  const float* Wk = (const float*)d_in[3];
  const float* bk = (const float*)d_in[4];
  const float* Wv = (const float*)d_in[5];
  const float* bv = (const float*)d_in[6];
  const int* mask = (const int*)d_in[7];
  float* out = (float*)d_out;

  f16* hsF  = (f16*)d_ws;                       // 8192*1024
  f16* wF   = hsF + (size_t)M_ * HID_;          // 3*1024*1024 (Wq, Wk, Wv)
  f16* qF   = wF + 3ull * HID_ * HID_;          // 8192*1024
  f16* kF   = qF + (size_t)M_ * HID_;           // 8192*1024
  f16* vF   = kF + (size_t)M_ * HID_;           // 8192*1024
  f16* keff = vF + (size_t)M_ * HID_;           // 64*2048*64
  f16* vt   = keff + (size_t)M_ * HID_;         // 64*64*2048

  cvt_all_k<<<dim3(8192 + 3072), 256, 0, stream>>>(hs, Wq, Wk, Wv, hsF, wF);
  proj_gemm_k<<<dim3(24, 64), 256, 0, stream>>>(hsF, wF, bq, bk, bv, qF);
  prep_kv_k<<<dim3(64, 32), 256, 0, stream>>>(kF, vF, keff, vt);
  attn_k<<<dim3(64, 8), 512, 0, stream>>>(qF, keff, vt, mask, out);
}